// Round 7
// baseline (1907.846 us; speedup 1.0000x reference)
//
#include <hip/hip_runtime.h>
#include <math.h>

#define NP 256
#define HID 512
#define BT 64
#define HHALF 256   // hidden processed per phase
#define KB 8        // LU panel width

// One workgroup per (w, b-tile of 64). Computes slater[w][b0..b0+63].
// Full f32 path: h0 staged in LDS as f32, 256 features per phase (64 KB).
__global__ __launch_bounds__(256) void k_mlp(
    const float* __restrict__ x,  const float* __restrict__ W0,
    const float* __restrict__ b0, const float* __restrict__ W1,
    const float* __restrict__ b1, const float* __restrict__ W2,
    const float* __restrict__ b2, float* __restrict__ slater)
{
    __shared__ __align__(16) float h0s[HHALF][BT];   // 64 KB
    const int w   = blockIdx.x;
    const int bt0 = blockIdx.y * BT;
    const int tid = threadIdx.x;

    const int bq = tid >> 5;   // 0..7  : rows bq*8 .. bq*8+7
    const int fq = tid & 31;   // 0..31 : cols fq*16 .. fq*16+15

    // layer-0 thread mapping
    const int bl = tid & 63;       // lane-major in b -> conflict-free LDS writes
    const int fo = tid >> 6;       // 0..3
    const int bg = bt0 + bl;
    const float x0 = x[bg*3+0], x1 = x[bg*3+1], x2 = x[bg*3+2];
    const float* W0w = W0 + (size_t)w*3*HID;
    const float* b0w = b0 + (size_t)w*HID;

    float acc[8][16];
    #pragma unroll
    for (int i = 0; i < 8; ++i)
        #pragma unroll
        for (int j = 0; j < 16; ++j) acc[i][j] = 0.0f;

    for (int ph = 0; ph < 2; ++ph) {
        if (ph) __syncthreads();            // prior phase's reads done before overwrite

        // ---- layer 0 (half): h0s[fl][b] = tanh(x[b,:] @ W0[w,:,f] + b0[w,f]) ----
        #pragma unroll 4
        for (int r = 0; r < HHALF/4; ++r) {
            int fl = r*4 + fo;              // whole wave shares f -> broadcast W0 loads
            int f  = ph*HHALF + fl;
            float v = x0*W0w[f] + x1*W0w[HID+f] + x2*W0w[2*HID+f] + b0w[f];
            h0s[fl][bl] = tanhf(v);
        }
        __syncthreads();

        // ---- layer 1 (half K): acc[i][j] += sum_c h0[bq*8+i][c]*W1[w][c][fq*16+j]
        const float* w1p = W1 + (size_t)w*HID*HID + (size_t)(ph*HHALF)*HID + fq*16;
        #pragma unroll 2
        for (int c = 0; c < HHALF; ++c) {
            float4 wv0 = *reinterpret_cast<const float4*>(w1p + 0);
            float4 wv1 = *reinterpret_cast<const float4*>(w1p + 4);
            float4 wv2 = *reinterpret_cast<const float4*>(w1p + 8);
            float4 wv3 = *reinterpret_cast<const float4*>(w1p + 12);
            w1p += HID;
            float4 h0a = *reinterpret_cast<const float4*>(&h0s[c][bq*8]);
            float4 h0b = *reinterpret_cast<const float4*>(&h0s[c][bq*8+4]);
            float a[8] = {h0a.x,h0a.y,h0a.z,h0a.w, h0b.x,h0b.y,h0b.z,h0b.w};
            #pragma unroll
            for (int i = 0; i < 8; ++i) {
                acc[i][0]  += a[i]*wv0.x; acc[i][1]  += a[i]*wv0.y;
                acc[i][2]  += a[i]*wv0.z; acc[i][3]  += a[i]*wv0.w;
                acc[i][4]  += a[i]*wv1.x; acc[i][5]  += a[i]*wv1.y;
                acc[i][6]  += a[i]*wv1.z; acc[i][7]  += a[i]*wv1.w;
                acc[i][8]  += a[i]*wv2.x; acc[i][9]  += a[i]*wv2.y;
                acc[i][10] += a[i]*wv2.z; acc[i][11] += a[i]*wv2.w;
                acc[i][12] += a[i]*wv3.x; acc[i][13] += a[i]*wv3.y;
                acc[i][14] += a[i]*wv3.z; acc[i][15] += a[i]*wv3.w;
            }
        }
    }

    // ---- epilogue: tanh(acc+b1) . W2 , reduce over fq, write slater row ----
    float bb[16], wt[16];
    {
        const float* b1w = b1 + (size_t)w*HID + fq*16;
        const float* W2w = W2 + (size_t)w*HID + fq*16;
        #pragma unroll
        for (int j4 = 0; j4 < 4; ++j4) {
            float4 bv = *reinterpret_cast<const float4*>(b1w + j4*4);
            float4 wv = *reinterpret_cast<const float4*>(W2w + j4*4);
            bb[j4*4+0]=bv.x; bb[j4*4+1]=bv.y; bb[j4*4+2]=bv.z; bb[j4*4+3]=bv.w;
            wt[j4*4+0]=wv.x; wt[j4*4+1]=wv.y; wt[j4*4+2]=wv.z; wt[j4*4+3]=wv.w;
        }
    }
    const float b2w = b2[w];
    #pragma unroll
    for (int i = 0; i < 8; ++i) {
        float part = 0.0f;
        #pragma unroll
        for (int j = 0; j < 16; ++j)
            part += tanhf(acc[i][j] + bb[j]) * wt[j];
        #pragma unroll
        for (int off = 16; off; off >>= 1)
            part += __shfl_xor(part, off, 32);   // reduce across fq (32-group)
        if (fq == 0)
            slater[w*NP + bt0 + bq*8 + i] = part + b2w;   // det(M^T)=det(M)
    }
}

// select pa[slot][c] (slot wave-uniform runtime, c compile-time), then one shfl
#define GETSH(dst, c, slot, srcl) do {                                        \
    float _v = ((slot)==0) ? pa[0][c] : ((slot)==1) ? pa[1][c]                \
             : ((slot)==2) ? pa[2][c] : pa[3][c];                             \
    (dst) = __shfl(_v, (srcl)); } while (0)

#define SETPA(slot, c, val) do {                                              \
    if ((slot)==0) pa[0][c]=(val); else if ((slot)==1) pa[1][c]=(val);        \
    else if ((slot)==2) pa[2][c]=(val); else pa[3][c]=(val); } while (0)

// Blocked (KB=8) partially-pivoted f32 LU, matrix register-resident.
// v4 vs round 6: 1024 threads; thread owns 4 rows x 16 cols (64 matrix regs,
// fits the 128-VGPR tier -> no bulk spill; round 6 needed ~190 at cap 128).
// cg = tid>>6 = wave id -> the 16-col slice is wave-uniform: STEP5's U
// broadcasts drop from 256 to 32 ds_read_b128 per thread per panel (one
// float4 feeds 16 FMAs), and the col-range check is a scalar branch.
// STEP5 row-activity check removed: rows/cols behind the frontier are dead
// storage (all later reads mask r>=k / read cols at the frontier), so
// updating them with garbage L is inert. Live-data FP ops unchanged ->
// absmax must stay exactly 32.0.
__global__ __launch_bounds__(1024, 4) void k_lu_blk(const float* __restrict__ A,
                                                    float* __restrict__ out)
{
    const int tid  = threadIdx.x;
    const int ri   = tid & 63;     // row-in-group (lane)
    const int cg   = tid >> 6;     // 16-col slice = wave id (wave-uniform)
    const int lane = tid;          // panel wave uses tid<64

    __shared__ float s_panel[NP][KB+1];   // stride 9: conflict-free scalar access
    __shared__ float s_stage[2*KB][260];  // staged rows (full 256 cols + pad)
    __shared__ float s_U[KB][260];        // TRSM'd U block
    __shared__ int   s_src[NP];
    __shared__ int   s_p[KB];
    __shared__ int   s_uslot[KB];
    __shared__ float s_piv[NP];

    float a[4][16];                       // rows q*64+ri, cols cg*16..cg*16+15
    {
        const float4* Ap = reinterpret_cast<const float4*>(A);
        #pragma unroll
        for (int q = 0; q < 4; ++q)
            #pragma unroll
            for (int u = 0; u < 4; ++u) {
                float4 v = Ap[(q*64+ri)*64 + cg*4 + u];
                a[q][u*4+0]=v.x; a[q][u*4+1]=v.y; a[q][u*4+2]=v.z; a[q][u*4+3]=v.w;
            }
    }

    for (int pi = 0; pi < NP/KB; ++pi) {
        const int k0 = pi * KB;
        __syncthreads();                                  // B0

        // ---- STEP 1: stage panel cols + init s_src ----
        if (tid < 256) s_src[tid] = tid;
        if (cg == (k0 >> 4)) {                            // wave-uniform
            if (((k0 >> 3) & 1) == 0) {
                #pragma unroll
                for (int q = 0; q < 4; ++q)
                    #pragma unroll
                    for (int c = 0; c < KB; ++c) s_panel[q*64+ri][c] = a[q][c];
            } else {
                #pragma unroll
                for (int q = 0; q < 4; ++q)
                    #pragma unroll
                    for (int c = 0; c < KB; ++c) s_panel[q*64+ri][c] = a[q][8+c];
            }
        }
        __syncthreads();                                  // B1

        // ---- STEP 2: wave 0 factorizes the 256x8 panel in registers ----
        if (tid < 64) {
            float pa[4][KB];
            #pragma unroll
            for (int q = 0; q < 4; ++q)
                #pragma unroll
                for (int c = 0; c < KB; ++c) pa[q][c] = s_panel[q*64+lane][c];

            int pvt[KB];
            #pragma unroll
            for (int kk = 0; kk < KB; ++kk) {
                const int k  = k0 + kk;
                const int sk = k >> 6, kl = k & 63;
                // argmax over rows >= k of |panel col kk|
                float bv = -1.0f; int bi = NP;
                #pragma unroll
                for (int q = 0; q < 4; ++q) {
                    int r = q*64 + lane;
                    float av = (r >= k) ? fabsf(pa[q][kk]) : -1.0f;
                    if (av > bv) { bv = av; bi = r; }
                }
                #pragma unroll
                for (int off = 32; off; off >>= 1) {
                    float ov = __shfl_xor(bv, off);
                    int   oi = __shfl_xor(bi, off);
                    if (ov > bv || (ov == bv && oi < bi)) { bv = ov; bi = oi; }
                }
                const int p = bi, sp = p >> 6, pl = p & 63;
                pvt[kk] = p;
                // FULL panel-row swap k<->p (all KB cols, incl. L cols c<kk);
                // urow[] captures the post-swap pivot row
                float urow[KB];
                #pragma unroll
                for (int c = 0; c < KB; ++c) {
                    float vk, vp;
                    GETSH(vk, c, sk, kl);
                    GETSH(vp, c, sp, pl);
                    if (lane == kl) SETPA(sk, c, vp);
                    if (lane == pl) SETPA(sp, c, vk);
                    urow[c] = vp;
                }
                const float pv = urow[kk];
                if (lane == 0) s_piv[k] = (p != k) ? -pv : pv;
                const float rp = 1.0f / pv;
                #pragma unroll
                for (int q = 0; q < 4; ++q) {
                    int r = q*64 + lane;
                    if (r > k) pa[q][kk] *= rp;
                }
                #pragma unroll
                for (int c = kk+1; c < KB; ++c) {
                    #pragma unroll
                    for (int q = 0; q < 4; ++q) {
                        int r = q*64 + lane;
                        if (r > k) pa[q][c] = fmaf(-pa[q][kk], urow[c], pa[q][c]);
                    }
                }
            }
            // write back factored panel + pivots
            #pragma unroll
            for (int q = 0; q < 4; ++q)
                #pragma unroll
                for (int c = 0; c < KB; ++c) s_panel[q*64+lane][c] = pa[q][c];
            if (lane == 0) {
                s_p[0]=pvt[0]; s_p[1]=pvt[1]; s_p[2]=pvt[2]; s_p[3]=pvt[3];
                s_p[4]=pvt[4]; s_p[5]=pvt[5]; s_p[6]=pvt[6]; s_p[7]=pvt[7];
            }
            // in-register swap simulation on 16 tracked positions
            int l8 = lane - 8;
            int psel = pvt[0];
            psel = (l8==1)?pvt[1]:psel; psel = (l8==2)?pvt[2]:psel;
            psel = (l8==3)?pvt[3]:psel; psel = (l8==4)?pvt[4]:psel;
            psel = (l8==5)?pvt[5]:psel; psel = (l8==6)?pvt[6]:psel;
            psel = (l8==7)?pvt[7]:psel;
            const int mypos = (lane < 8) ? (k0 + lane) : psel;
            int cur = mypos;
            #pragma unroll
            for (int s = 0; s < KB; ++s) {
                int cA = __shfl(cur, s);        // content at position k0+s
                int cB = __shfl(cur, 8+s);      // content at position pvt[s]
                int ks = k0 + s, ps = pvt[s];
                if (mypos == ks) cur = cB;
                else if (mypos == ps) cur = cA;
            }
            if (lane < 16) s_src[mypos] = cur;
            if (lane < 8) {
                int c = cur, slot = 8;
                slot = (pvt[0]==c)? 8:slot; slot = (pvt[1]==c)? 9:slot;
                slot = (pvt[2]==c)?10:slot; slot = (pvt[3]==c)?11:slot;
                slot = (pvt[4]==c)?12:slot; slot = (pvt[5]==c)?13:slot;
                slot = (pvt[6]==c)?14:slot; slot = (pvt[7]==c)?15:slot;
                if (c >= k0 && c < k0+KB) slot = c - k0;
                s_uslot[lane] = slot;
            }
        }
        __syncthreads();                                  // B2

        int pp[KB];
        #pragma unroll
        for (int s = 0; s < KB; ++s) pp[s] = s_p[s];

        // ---- STEP 3: stage affected rows (pre-swap content, by position) ----
        #pragma unroll
        for (int q = 0; q < 4; ++q) {
            const int iq = q*64 + ri;
            if (iq >= k0 && iq < k0+KB) {
                const int sl = iq - k0;
                #pragma unroll
                for (int u = 0; u < 4; ++u) {
                    float4 v; v.x=a[q][u*4]; v.y=a[q][u*4+1];
                    v.z=a[q][u*4+2]; v.w=a[q][u*4+3];
                    *reinterpret_cast<float4*>(&s_stage[sl][cg*16+u*4]) = v;
                }
            }
            #pragma unroll
            for (int s = 0; s < KB; ++s) {
                if (iq == pp[s]) {
                    #pragma unroll
                    for (int u = 0; u < 4; ++u) {
                        float4 v; v.x=a[q][u*4]; v.y=a[q][u*4+1];
                        v.z=a[q][u*4+2]; v.w=a[q][u*4+3];
                        *reinterpret_cast<float4*>(&s_stage[KB+s][cg*16+u*4]) = v;
                    }
                }
            }
        }
        __syncthreads();                                  // B3

        // ---- STEP 4a: apply row permutation from stage ----
        #pragma unroll
        for (int q = 0; q < 4; ++q) {
            const int iq = q*64 + ri;
            const int sr = s_src[iq];
            if (sr != iq) {
                int slot = 8;
                #pragma unroll
                for (int s = 0; s < KB; ++s) slot = (pp[s]==sr) ? KB+s : slot;
                if (sr >= k0 && sr < k0+KB) slot = sr - k0;
                #pragma unroll
                for (int u = 0; u < 4; ++u) {
                    float4 v = *reinterpret_cast<const float4*>(&s_stage[slot][cg*16+u*4]);
                    a[q][u*4+0]=v.x; a[q][u*4+1]=v.y; a[q][u*4+2]=v.z; a[q][u*4+3]=v.w;
                }
            }
        }
        // ---- STEP 4b: TRSM of U block, column-parallel (tid<256, col j=tid) ----
        if (tid < 256) {
            const int j = tid;
            int us[KB];
            #pragma unroll
            for (int m = 0; m < KB; ++m) us[m] = s_uslot[m];
            float uv[KB];
            #pragma unroll
            for (int m = 0; m < KB; ++m) {
                float v = s_stage[us[m]][j];
                #pragma unroll
                for (int s = 0; s < KB; ++s)
                    if (s < m) v = fmaf(-s_panel[k0+m][s], uv[s], v);
                uv[m] = v;
                s_U[m][j] = v;
            }
        }
        __syncthreads();                                  // B4

        // ---- STEP 5: rank-8 trailing update (cols >= k0+8, ALL rows —
        //      behind-frontier rows are dead storage, writes inert) ----
        float L0[4][KB];
        #pragma unroll
        for (int q = 0; q < 4; ++q)
            #pragma unroll
            for (int m = 0; m < KB; ++m) L0[q][m] = s_panel[q*64+ri][m];
        #pragma unroll
        for (int u4 = 0; u4 < 4; ++u4) {
            if (cg*16 + u4*4 + 3 >= k0 + KB) {            // wave-uniform branch
                #pragma unroll
                for (int m = 0; m < KB; ++m) {
                    const float4 uv = *reinterpret_cast<const float4*>(&s_U[m][cg*16+u4*4]);
                    #pragma unroll
                    for (int q = 0; q < 4; ++q) {
                        a[q][u4*4+0] = fmaf(-L0[q][m], uv.x, a[q][u4*4+0]);
                        a[q][u4*4+1] = fmaf(-L0[q][m], uv.y, a[q][u4*4+1]);
                        a[q][u4*4+2] = fmaf(-L0[q][m], uv.z, a[q][u4*4+2]);
                        a[q][u4*4+3] = fmaf(-L0[q][m], uv.w, a[q][u4*4+3]);
                    }
                }
            }
        }
    }
    __syncthreads();

    // ---- logdet = sum log|piv| (f64 accum), sign = parity of negatives ----
    if (tid < 64) {
        double ld = 0.0; int neg = 0;
        #pragma unroll
        for (int q = 0; q < 4; ++q) {
            float pv = s_piv[q*64 + tid];
            ld  += (double)logf(fabsf(pv));
            neg ^= (pv < 0.0f) ? 1 : 0;
        }
        #pragma unroll
        for (int off = 32; off; off >>= 1) {
            ld  += __shfl_xor(ld, off);
            neg ^= __shfl_xor(neg, off);
        }
        if (tid == 0) { out[0] = neg ? -1.0f : 1.0f; out[1] = (float)ld; }
    }
}

extern "C" void kernel_launch(void* const* d_in, const int* in_sizes, int n_in,
                              void* d_out, int out_size, void* d_ws, size_t ws_size,
                              hipStream_t stream)
{
    const float* x  = (const float*)d_in[0];
    const float* W0 = (const float*)d_in[1];
    const float* b0 = (const float*)d_in[2];
    const float* W1 = (const float*)d_in[3];
    const float* b1 = (const float*)d_in[4];
    const float* W2 = (const float*)d_in[5];
    const float* b2 = (const float*)d_in[6];
    float* out    = (float*)d_out;
    float* slater = (float*)d_ws;           // 256*256*4 = 256 KB scratch

    k_mlp<<<dim3(NP, NP/BT), 256, 0, stream>>>(x, W0, b0, W1, b1, W2, b2, slater);
    k_lu_blk<<<1, 1024, 0, stream>>>(slater, out);
}

// Round 8
// 1901.143 us; speedup vs baseline: 1.0035x; 1.0035x over previous
//
#include <hip/hip_runtime.h>
#include <math.h>

#define NP 256
#define HID 512
#define BT 64
#define HHALF 256   // hidden processed per phase
#define KB 8        // LU panel width

// One workgroup per (w, b-tile of 64). Computes slater[w][b0..b0+63].
// Full f32 path: h0 staged in LDS as f32, 256 features per phase (64 KB).
__global__ __launch_bounds__(256) void k_mlp(
    const float* __restrict__ x,  const float* __restrict__ W0,
    const float* __restrict__ b0, const float* __restrict__ W1,
    const float* __restrict__ b1, const float* __restrict__ W2,
    const float* __restrict__ b2, float* __restrict__ slater)
{
    __shared__ __align__(16) float h0s[HHALF][BT];   // 64 KB
    const int w   = blockIdx.x;
    const int bt0 = blockIdx.y * BT;
    const int tid = threadIdx.x;

    const int bq = tid >> 5;   // 0..7  : rows bq*8 .. bq*8+7
    const int fq = tid & 31;   // 0..31 : cols fq*16 .. fq*16+15

    // layer-0 thread mapping
    const int bl = tid & 63;       // lane-major in b -> conflict-free LDS writes
    const int fo = tid >> 6;       // 0..3
    const int bg = bt0 + bl;
    const float x0 = x[bg*3+0], x1 = x[bg*3+1], x2 = x[bg*3+2];
    const float* W0w = W0 + (size_t)w*3*HID;
    const float* b0w = b0 + (size_t)w*HID;

    float acc[8][16];
    #pragma unroll
    for (int i = 0; i < 8; ++i)
        #pragma unroll
        for (int j = 0; j < 16; ++j) acc[i][j] = 0.0f;

    for (int ph = 0; ph < 2; ++ph) {
        if (ph) __syncthreads();            // prior phase's reads done before overwrite

        // ---- layer 0 (half): h0s[fl][b] = tanh(x[b,:] @ W0[w,:,f] + b0[w,f]) ----
        #pragma unroll 4
        for (int r = 0; r < HHALF/4; ++r) {
            int fl = r*4 + fo;              // whole wave shares f -> broadcast W0 loads
            int f  = ph*HHALF + fl;
            float v = x0*W0w[f] + x1*W0w[HID+f] + x2*W0w[2*HID+f] + b0w[f];
            h0s[fl][bl] = tanhf(v);
        }
        __syncthreads();

        // ---- layer 1 (half K): acc[i][j] += sum_c h0[bq*8+i][c]*W1[w][c][fq*16+j]
        const float* w1p = W1 + (size_t)w*HID*HID + (size_t)(ph*HHALF)*HID + fq*16;
        #pragma unroll 2
        for (int c = 0; c < HHALF; ++c) {
            float4 wv0 = *reinterpret_cast<const float4*>(w1p + 0);
            float4 wv1 = *reinterpret_cast<const float4*>(w1p + 4);
            float4 wv2 = *reinterpret_cast<const float4*>(w1p + 8);
            float4 wv3 = *reinterpret_cast<const float4*>(w1p + 12);
            w1p += HID;
            float4 h0a = *reinterpret_cast<const float4*>(&h0s[c][bq*8]);
            float4 h0b = *reinterpret_cast<const float4*>(&h0s[c][bq*8+4]);
            float a[8] = {h0a.x,h0a.y,h0a.z,h0a.w, h0b.x,h0b.y,h0b.z,h0b.w};
            #pragma unroll
            for (int i = 0; i < 8; ++i) {
                acc[i][0]  += a[i]*wv0.x; acc[i][1]  += a[i]*wv0.y;
                acc[i][2]  += a[i]*wv0.z; acc[i][3]  += a[i]*wv0.w;
                acc[i][4]  += a[i]*wv1.x; acc[i][5]  += a[i]*wv1.y;
                acc[i][6]  += a[i]*wv1.z; acc[i][7]  += a[i]*wv1.w;
                acc[i][8]  += a[i]*wv2.x; acc[i][9]  += a[i]*wv2.y;
                acc[i][10] += a[i]*wv2.z; acc[i][11] += a[i]*wv2.w;
                acc[i][12] += a[i]*wv3.x; acc[i][13] += a[i]*wv3.y;
                acc[i][14] += a[i]*wv3.z; acc[i][15] += a[i]*wv3.w;
            }
        }
    }

    // ---- epilogue: tanh(acc+b1) . W2 , reduce over fq, write slater row ----
    float bb[16], wt[16];
    {
        const float* b1w = b1 + (size_t)w*HID + fq*16;
        const float* W2w = W2 + (size_t)w*HID + fq*16;
        #pragma unroll
        for (int j4 = 0; j4 < 4; ++j4) {
            float4 bv = *reinterpret_cast<const float4*>(b1w + j4*4);
            float4 wv = *reinterpret_cast<const float4*>(W2w + j4*4);
            bb[j4*4+0]=bv.x; bb[j4*4+1]=bv.y; bb[j4*4+2]=bv.z; bb[j4*4+3]=bv.w;
            wt[j4*4+0]=wv.x; wt[j4*4+1]=wv.y; wt[j4*4+2]=wv.z; wt[j4*4+3]=wv.w;
        }
    }
    const float b2w = b2[w];
    #pragma unroll
    for (int i = 0; i < 8; ++i) {
        float part = 0.0f;
        #pragma unroll
        for (int j = 0; j < 16; ++j)
            part += tanhf(acc[i][j] + bb[j]) * wt[j];
        #pragma unroll
        for (int off = 16; off; off >>= 1)
            part += __shfl_xor(part, off, 32);   // reduce across fq (32-group)
        if (fq == 0)
            slater[w*NP + bt0 + bq*8 + i] = part + b2w;   // det(M^T)=det(M)
    }
}

__device__ __forceinline__ float rf_f32(float x) {
    return __uint_as_float(__builtin_amdgcn_readfirstlane(__float_as_uint(x)));
}

// select pa[slot][c] (slot wave-uniform runtime, c compile-time), then one shfl
#define GETSH(dst, c, slot, srcl) do {                                        \
    float _v = ((slot)==0) ? pa[0][c] : ((slot)==1) ? pa[1][c]                \
             : ((slot)==2) ? pa[2][c] : pa[3][c];                             \
    (dst) = __shfl(_v, (srcl)); } while (0)

#define SETPA(slot, c, val) do {                                              \
    if ((slot)==0) pa[0][c]=(val); else if ((slot)==1) pa[1][c]=(val);        \
    else if ((slot)==2) pa[2][c]=(val); else pa[3][c]=(val); } while (0)

// Blocked (KB=8) partially-pivoted f32 LU, matrix register-resident.
// v5 vs round 7: __launch_bounds__(1024, 1) — hipcc's 2nd arg behaves as min
// BLOCKS/CU ((512,2)->128 VGPR, (1024,4)->clamped 2 blocks->64 VGPR, massive
// spill WRITE_SIZE=252KB). 1 block/CU = 16 waves = 4/SIMD -> VGPR cap 128
// (also the hard max for a 1024-thread block under either semantics).
// Wave-0 peak cut ~127 -> ~110 by forcing wave-uniform shfl results (pvt, p,
// urow, pv, rp) into SGPRs via readfirstlane. FP op sequence unchanged ->
// absmax must stay exactly 32.0.
__global__ __launch_bounds__(1024, 1) void k_lu_blk(const float* __restrict__ A,
                                                    float* __restrict__ out)
{
    const int tid  = threadIdx.x;
    const int ri   = tid & 63;     // row-in-group (lane)
    const int cg   = tid >> 6;     // 16-col slice = wave id (wave-uniform)
    const int lane = tid;          // panel wave uses tid<64

    __shared__ float s_panel[NP][KB+1];   // stride 9: conflict-free scalar access
    __shared__ float s_stage[2*KB][260];  // staged rows (full 256 cols + pad)
    __shared__ float s_U[KB][260];        // TRSM'd U block
    __shared__ int   s_src[NP];
    __shared__ int   s_p[KB];
    __shared__ int   s_uslot[KB];
    __shared__ float s_piv[NP];

    float a[4][16];                       // rows q*64+ri, cols cg*16..cg*16+15
    {
        const float4* Ap = reinterpret_cast<const float4*>(A);
        #pragma unroll
        for (int q = 0; q < 4; ++q)
            #pragma unroll
            for (int u = 0; u < 4; ++u) {
                float4 v = Ap[(q*64+ri)*64 + cg*4 + u];
                a[q][u*4+0]=v.x; a[q][u*4+1]=v.y; a[q][u*4+2]=v.z; a[q][u*4+3]=v.w;
            }
    }

    for (int pi = 0; pi < NP/KB; ++pi) {
        const int k0 = pi * KB;
        __syncthreads();                                  // B0

        // ---- STEP 1: stage panel cols + init s_src ----
        if (tid < 256) s_src[tid] = tid;
        if (cg == (k0 >> 4)) {                            // wave-uniform
            if (((k0 >> 3) & 1) == 0) {
                #pragma unroll
                for (int q = 0; q < 4; ++q)
                    #pragma unroll
                    for (int c = 0; c < KB; ++c) s_panel[q*64+ri][c] = a[q][c];
            } else {
                #pragma unroll
                for (int q = 0; q < 4; ++q)
                    #pragma unroll
                    for (int c = 0; c < KB; ++c) s_panel[q*64+ri][c] = a[q][8+c];
            }
        }
        __syncthreads();                                  // B1

        // ---- STEP 2: wave 0 factorizes the 256x8 panel in registers ----
        if (tid < 64) {
            float pa[4][KB];
            #pragma unroll
            for (int q = 0; q < 4; ++q)
                #pragma unroll
                for (int c = 0; c < KB; ++c) pa[q][c] = s_panel[q*64+lane][c];

            int pvt[KB];
            #pragma unroll
            for (int kk = 0; kk < KB; ++kk) {
                const int k  = k0 + kk;
                const int sk = k >> 6, kl = k & 63;
                // argmax over rows >= k of |panel col kk|
                float bv = -1.0f; int bi = NP;
                #pragma unroll
                for (int q = 0; q < 4; ++q) {
                    int r = q*64 + lane;
                    float av = (r >= k) ? fabsf(pa[q][kk]) : -1.0f;
                    if (av > bv) { bv = av; bi = r; }
                }
                #pragma unroll
                for (int off = 32; off; off >>= 1) {
                    float ov = __shfl_xor(bv, off);
                    int   oi = __shfl_xor(bi, off);
                    if (ov > bv || (ov == bv && oi < bi)) { bv = ov; bi = oi; }
                }
                // post-reduce bi is wave-uniform -> pin to SGPR
                const int p = __builtin_amdgcn_readfirstlane(bi);
                const int sp = p >> 6, pl = p & 63;
                pvt[kk] = p;
                // FULL panel-row swap k<->p (all KB cols, incl. L cols c<kk);
                // urow[] captures the post-swap pivot row (uniform -> SGPR)
                float urow[KB];
                #pragma unroll
                for (int c = 0; c < KB; ++c) {
                    float vk, vp;
                    GETSH(vk, c, sk, kl);
                    GETSH(vp, c, sp, pl);
                    if (lane == kl) SETPA(sk, c, vp);
                    if (lane == pl) SETPA(sp, c, vk);
                    urow[c] = rf_f32(vp);
                }
                const float pv = urow[kk];
                if (lane == 0) s_piv[k] = (p != k) ? -pv : pv;
                const float rp = rf_f32(1.0f / pv);
                #pragma unroll
                for (int q = 0; q < 4; ++q) {
                    int r = q*64 + lane;
                    if (r > k) pa[q][kk] *= rp;
                }
                #pragma unroll
                for (int c = kk+1; c < KB; ++c) {
                    #pragma unroll
                    for (int q = 0; q < 4; ++q) {
                        int r = q*64 + lane;
                        if (r > k) pa[q][c] = fmaf(-pa[q][kk], urow[c], pa[q][c]);
                    }
                }
            }
            // write back factored panel + pivots
            #pragma unroll
            for (int q = 0; q < 4; ++q)
                #pragma unroll
                for (int c = 0; c < KB; ++c) s_panel[q*64+lane][c] = pa[q][c];
            if (lane == 0) {
                s_p[0]=pvt[0]; s_p[1]=pvt[1]; s_p[2]=pvt[2]; s_p[3]=pvt[3];
                s_p[4]=pvt[4]; s_p[5]=pvt[5]; s_p[6]=pvt[6]; s_p[7]=pvt[7];
            }
            // in-register swap simulation on 16 tracked positions
            int l8 = lane - 8;
            int psel = pvt[0];
            psel = (l8==1)?pvt[1]:psel; psel = (l8==2)?pvt[2]:psel;
            psel = (l8==3)?pvt[3]:psel; psel = (l8==4)?pvt[4]:psel;
            psel = (l8==5)?pvt[5]:psel; psel = (l8==6)?pvt[6]:psel;
            psel = (l8==7)?pvt[7]:psel;
            const int mypos = (lane < 8) ? (k0 + lane) : psel;
            int cur = mypos;
            #pragma unroll
            for (int s = 0; s < KB; ++s) {
                int cA = __shfl(cur, s);        // content at position k0+s
                int cB = __shfl(cur, 8+s);      // content at position pvt[s]
                int ks = k0 + s, ps = pvt[s];
                if (mypos == ks) cur = cB;
                else if (mypos == ps) cur = cA;
            }
            if (lane < 16) s_src[mypos] = cur;
            if (lane < 8) {
                int c = cur, slot = 8;
                slot = (pvt[0]==c)? 8:slot; slot = (pvt[1]==c)? 9:slot;
                slot = (pvt[2]==c)?10:slot; slot = (pvt[3]==c)?11:slot;
                slot = (pvt[4]==c)?12:slot; slot = (pvt[5]==c)?13:slot;
                slot = (pvt[6]==c)?14:slot; slot = (pvt[7]==c)?15:slot;
                if (c >= k0 && c < k0+KB) slot = c - k0;
                s_uslot[lane] = slot;
            }
        }
        __syncthreads();                                  // B2

        int pp[KB];
        #pragma unroll
        for (int s = 0; s < KB; ++s) pp[s] = s_p[s];

        // ---- STEP 3: stage affected rows (pre-swap content, by position) ----
        #pragma unroll
        for (int q = 0; q < 4; ++q) {
            const int iq = q*64 + ri;
            if (iq >= k0 && iq < k0+KB) {
                const int sl = iq - k0;
                #pragma unroll
                for (int u = 0; u < 4; ++u) {
                    float4 v; v.x=a[q][u*4]; v.y=a[q][u*4+1];
                    v.z=a[q][u*4+2]; v.w=a[q][u*4+3];
                    *reinterpret_cast<float4*>(&s_stage[sl][cg*16+u*4]) = v;
                }
            }
            #pragma unroll
            for (int s = 0; s < KB; ++s) {
                if (iq == pp[s]) {
                    #pragma unroll
                    for (int u = 0; u < 4; ++u) {
                        float4 v; v.x=a[q][u*4]; v.y=a[q][u*4+1];
                        v.z=a[q][u*4+2]; v.w=a[q][u*4+3];
                        *reinterpret_cast<float4*>(&s_stage[KB+s][cg*16+u*4]) = v;
                    }
                }
            }
        }
        __syncthreads();                                  // B3

        // ---- STEP 4a: apply row permutation from stage ----
        #pragma unroll
        for (int q = 0; q < 4; ++q) {
            const int iq = q*64 + ri;
            const int sr = s_src[iq];
            if (sr != iq) {
                int slot = 8;
                #pragma unroll
                for (int s = 0; s < KB; ++s) slot = (pp[s]==sr) ? KB+s : slot;
                if (sr >= k0 && sr < k0+KB) slot = sr - k0;
                #pragma unroll
                for (int u = 0; u < 4; ++u) {
                    float4 v = *reinterpret_cast<const float4*>(&s_stage[slot][cg*16+u*4]);
                    a[q][u*4+0]=v.x; a[q][u*4+1]=v.y; a[q][u*4+2]=v.z; a[q][u*4+3]=v.w;
                }
            }
        }
        // ---- STEP 4b: TRSM of U block, column-parallel (tid<256, col j=tid) ----
        if (tid < 256) {
            const int j = tid;
            int us[KB];
            #pragma unroll
            for (int m = 0; m < KB; ++m) us[m] = s_uslot[m];
            float uv[KB];
            #pragma unroll
            for (int m = 0; m < KB; ++m) {
                float v = s_stage[us[m]][j];
                #pragma unroll
                for (int s = 0; s < KB; ++s)
                    if (s < m) v = fmaf(-s_panel[k0+m][s], uv[s], v);
                uv[m] = v;
                s_U[m][j] = v;
            }
        }
        __syncthreads();                                  // B4

        // ---- STEP 5: rank-8 trailing update (cols >= k0+8, ALL rows —
        //      behind-frontier rows are dead storage, writes inert) ----
        float L0[4][KB];
        #pragma unroll
        for (int q = 0; q < 4; ++q)
            #pragma unroll
            for (int m = 0; m < KB; ++m) L0[q][m] = s_panel[q*64+ri][m];
        #pragma unroll
        for (int u4 = 0; u4 < 4; ++u4) {
            if (cg*16 + u4*4 + 3 >= k0 + KB) {            // wave-uniform branch
                #pragma unroll
                for (int m = 0; m < KB; ++m) {
                    const float4 uv = *reinterpret_cast<const float4*>(&s_U[m][cg*16+u4*4]);
                    #pragma unroll
                    for (int q = 0; q < 4; ++q) {
                        a[q][u4*4+0] = fmaf(-L0[q][m], uv.x, a[q][u4*4+0]);
                        a[q][u4*4+1] = fmaf(-L0[q][m], uv.y, a[q][u4*4+1]);
                        a[q][u4*4+2] = fmaf(-L0[q][m], uv.z, a[q][u4*4+2]);
                        a[q][u4*4+3] = fmaf(-L0[q][m], uv.w, a[q][u4*4+3]);
                    }
                }
            }
        }
    }
    __syncthreads();

    // ---- logdet = sum log|piv| (f64 accum), sign = parity of negatives ----
    if (tid < 64) {
        double ld = 0.0; int neg = 0;
        #pragma unroll
        for (int q = 0; q < 4; ++q) {
            float pv = s_piv[q*64 + tid];
            ld  += (double)logf(fabsf(pv));
            neg ^= (pv < 0.0f) ? 1 : 0;
        }
        #pragma unroll
        for (int off = 32; off; off >>= 1) {
            ld  += __shfl_xor(ld, off);
            neg ^= __shfl_xor(neg, off);
        }
        if (tid == 0) { out[0] = neg ? -1.0f : 1.0f; out[1] = (float)ld; }
    }
}

extern "C" void kernel_launch(void* const* d_in, const int* in_sizes, int n_in,
                              void* d_out, int out_size, void* d_ws, size_t ws_size,
                              hipStream_t stream)
{
    const float* x  = (const float*)d_in[0];
    const float* W0 = (const float*)d_in[1];
    const float* b0 = (const float*)d_in[2];
    const float* W1 = (const float*)d_in[3];
    const float* b1 = (const float*)d_in[4];
    const float* W2 = (const float*)d_in[5];
    const float* b2 = (const float*)d_in[6];
    float* out    = (float*)d_out;
    float* slater = (float*)d_ws;           // 256*256*4 = 256 KB scratch

    k_mlp<<<dim3(NP, NP/BT), 256, 0, stream>>>(x, W0, b0, W1, b1, W2, b2, slater);
    k_lu_blk<<<1, 1024, 0, stream>>>(slater, out);
}

// Round 9
// 1593.283 us; speedup vs baseline: 1.1974x; 1.1932x over previous
//
#include <hip/hip_runtime.h>
#include <math.h>

#define NP 256
#define HID 512
#define BT 64
#define HHALF 256   // hidden processed per phase
#define KB 8        // LU panel width

// One workgroup per (w, b-tile of 64). Computes slater[w][b0..b0+63].
// Full f32 path: h0 staged in LDS as f32, 256 features per phase (64 KB).
__global__ __launch_bounds__(256) void k_mlp(
    const float* __restrict__ x,  const float* __restrict__ W0,
    const float* __restrict__ b0, const float* __restrict__ W1,
    const float* __restrict__ b1, const float* __restrict__ W2,
    const float* __restrict__ b2, float* __restrict__ slater)
{
    __shared__ __align__(16) float h0s[HHALF][BT];   // 64 KB
    const int w   = blockIdx.x;
    const int bt0 = blockIdx.y * BT;
    const int tid = threadIdx.x;

    const int bq = tid >> 5;   // 0..7  : rows bq*8 .. bq*8+7
    const int fq = tid & 31;   // 0..31 : cols fq*16 .. fq*16+15

    // layer-0 thread mapping
    const int bl = tid & 63;       // lane-major in b -> conflict-free LDS writes
    const int fo = tid >> 6;       // 0..3
    const int bg = bt0 + bl;
    const float x0 = x[bg*3+0], x1 = x[bg*3+1], x2 = x[bg*3+2];
    const float* W0w = W0 + (size_t)w*3*HID;
    const float* b0w = b0 + (size_t)w*HID;

    float acc[8][16];
    #pragma unroll
    for (int i = 0; i < 8; ++i)
        #pragma unroll
        for (int j = 0; j < 16; ++j) acc[i][j] = 0.0f;

    for (int ph = 0; ph < 2; ++ph) {
        if (ph) __syncthreads();            // prior phase's reads done before overwrite

        // ---- layer 0 (half): h0s[fl][b] = tanh(x[b,:] @ W0[w,:,f] + b0[w,f]) ----
        #pragma unroll 4
        for (int r = 0; r < HHALF/4; ++r) {
            int fl = r*4 + fo;              // whole wave shares f -> broadcast W0 loads
            int f  = ph*HHALF + fl;
            float v = x0*W0w[f] + x1*W0w[HID+f] + x2*W0w[2*HID+f] + b0w[f];
            h0s[fl][bl] = tanhf(v);
        }
        __syncthreads();

        // ---- layer 1 (half K): acc[i][j] += sum_c h0[bq*8+i][c]*W1[w][c][fq*16+j]
        const float* w1p = W1 + (size_t)w*HID*HID + (size_t)(ph*HHALF)*HID + fq*16;
        #pragma unroll 2
        for (int c = 0; c < HHALF; ++c) {
            float4 wv0 = *reinterpret_cast<const float4*>(w1p + 0);
            float4 wv1 = *reinterpret_cast<const float4*>(w1p + 4);
            float4 wv2 = *reinterpret_cast<const float4*>(w1p + 8);
            float4 wv3 = *reinterpret_cast<const float4*>(w1p + 12);
            w1p += HID;
            float4 h0a = *reinterpret_cast<const float4*>(&h0s[c][bq*8]);
            float4 h0b = *reinterpret_cast<const float4*>(&h0s[c][bq*8+4]);
            float a[8] = {h0a.x,h0a.y,h0a.z,h0a.w, h0b.x,h0b.y,h0b.z,h0b.w};
            #pragma unroll
            for (int i = 0; i < 8; ++i) {
                acc[i][0]  += a[i]*wv0.x; acc[i][1]  += a[i]*wv0.y;
                acc[i][2]  += a[i]*wv0.z; acc[i][3]  += a[i]*wv0.w;
                acc[i][4]  += a[i]*wv1.x; acc[i][5]  += a[i]*wv1.y;
                acc[i][6]  += a[i]*wv1.z; acc[i][7]  += a[i]*wv1.w;
                acc[i][8]  += a[i]*wv2.x; acc[i][9]  += a[i]*wv2.y;
                acc[i][10] += a[i]*wv2.z; acc[i][11] += a[i]*wv2.w;
                acc[i][12] += a[i]*wv3.x; acc[i][13] += a[i]*wv3.y;
                acc[i][14] += a[i]*wv3.z; acc[i][15] += a[i]*wv3.w;
            }
        }
    }

    // ---- epilogue: tanh(acc+b1) . W2 , reduce over fq, write slater row ----
    float bb[16], wt[16];
    {
        const float* b1w = b1 + (size_t)w*HID + fq*16;
        const float* W2w = W2 + (size_t)w*HID + fq*16;
        #pragma unroll
        for (int j4 = 0; j4 < 4; ++j4) {
            float4 bv = *reinterpret_cast<const float4*>(b1w + j4*4);
            float4 wv = *reinterpret_cast<const float4*>(W2w + j4*4);
            bb[j4*4+0]=bv.x; bb[j4*4+1]=bv.y; bb[j4*4+2]=bv.z; bb[j4*4+3]=bv.w;
            wt[j4*4+0]=wv.x; wt[j4*4+1]=wv.y; wt[j4*4+2]=wv.z; wt[j4*4+3]=wv.w;
        }
    }
    const float b2w = b2[w];
    #pragma unroll
    for (int i = 0; i < 8; ++i) {
        float part = 0.0f;
        #pragma unroll
        for (int j = 0; j < 16; ++j)
            part += tanhf(acc[i][j] + bb[j]) * wt[j];
        #pragma unroll
        for (int off = 16; off; off >>= 1)
            part += __shfl_xor(part, off, 32);   // reduce across fq (32-group)
        if (fq == 0)
            slater[w*NP + bt0 + bq*8 + i] = part + b2w;   // det(M^T)=det(M)
    }
}

__device__ __forceinline__ float rf_f32(float x) {
    return __uint_as_float(__builtin_amdgcn_readfirstlane(__float_as_uint(x)));
}

// select pa[slot][c] (slot wave-uniform runtime, c compile-time), then one shfl
#define GETSH(dst, c, slot, srcl) do {                                        \
    float _v = ((slot)==0) ? pa[0][c] : ((slot)==1) ? pa[1][c]                \
             : ((slot)==2) ? pa[2][c] : pa[3][c];                             \
    (dst) = __shfl(_v, (srcl)); } while (0)

#define SETPA(slot, c, val) do {                                              \
    if ((slot)==0) pa[0][c]=(val); else if ((slot)==1) pa[1][c]=(val);        \
    else if ((slot)==2) pa[2][c]=(val); else pa[3][c]=(val); } while (0)

#define STG_CASE(o)                                                           \
    s_panel[i][0]=a[(o)*8+0]; s_panel[i][1]=a[(o)*8+1];                       \
    s_panel[i][2]=a[(o)*8+2]; s_panel[i][3]=a[(o)*8+3];                       \
    s_panel[i][4]=a[(o)*8+4]; s_panel[i][5]=a[(o)*8+5];                       \
    s_panel[i][6]=a[(o)*8+6]; s_panel[i][7]=a[(o)*8+7];

// Blocked (KB=8) partially-pivoted f32 LU, matrix register-resident.
// v6: round-6 512-thread structure (verified, absmax 32.0) with
// __launch_bounds__(512, 1): 8 waves = 2 waves/SIMD -> VGPR cap 256 under
// BOTH plausible launch-bounds semantics (min-blocks/CU or min-waves/EU).
// Round 6's cap-128 left ~60 regs spilling (WRITE 8KB, VGPR=128); 1024-thread
// variants are stuck at the 64-reg tier (rounds 7/8: VGPR=64, WRITE 260KB).
// Live set ~190 < 256 -> zero bulk spill expected. Wave-0 panel keeps
// readfirstlane pinning of wave-uniform values (p, urow, rp) in SGPRs.
// FP op sequence unchanged -> absmax must stay exactly 32.0.
__global__ __launch_bounds__(512, 1) void k_lu_blk(const float* __restrict__ A,
                                                   float* __restrict__ out)
{
    const int tid   = threadIdx.x;
    const int i     = tid & 255;    // row
    const int jc    = tid >> 8;     // column half (wave-uniform): 0 or 1
    const int jbase = jc * 128;
    const int lane  = tid;          // panel wave uses tid<64

    __shared__ float s_panel[NP][KB+1];   // stride 9: conflict-free scalar access
    __shared__ float s_stage[2*KB][260];  // staged rows (full 256 cols + pad)
    __shared__ float s_U[KB][260];        // TRSM'd U block
    __shared__ int   s_src[NP];
    __shared__ int   s_p[KB];
    __shared__ int   s_uslot[KB];
    __shared__ float s_piv[NP];

    float a[128];
    {
        const float4* Ap = reinterpret_cast<const float4*>(A);
        #pragma unroll
        for (int u = 0; u < 32; ++u) {
            float4 v = Ap[i*64 + jc*32 + u];
            a[u*4+0]=v.x; a[u*4+1]=v.y; a[u*4+2]=v.z; a[u*4+3]=v.w;
        }
    }

    for (int pi = 0; pi < NP/KB; ++pi) {
        const int k0   = pi * KB;
        const int jc_p = k0 >> 7;           // which 128-col half holds the panel
        __syncthreads();                                  // B0

        // ---- STEP 1: stage panel cols + init s_src ----
        if (jc == 0) s_src[i] = i;
        if (jc == jc_p) {
            switch ((k0 & 127) >> 3) {
                case 0:  { STG_CASE(0)  } break;  case 1:  { STG_CASE(1)  } break;
                case 2:  { STG_CASE(2)  } break;  case 3:  { STG_CASE(3)  } break;
                case 4:  { STG_CASE(4)  } break;  case 5:  { STG_CASE(5)  } break;
                case 6:  { STG_CASE(6)  } break;  case 7:  { STG_CASE(7)  } break;
                case 8:  { STG_CASE(8)  } break;  case 9:  { STG_CASE(9)  } break;
                case 10: { STG_CASE(10) } break;  case 11: { STG_CASE(11) } break;
                case 12: { STG_CASE(12) } break;  case 13: { STG_CASE(13) } break;
                case 14: { STG_CASE(14) } break;  default: { STG_CASE(15) } break;
            }
        }
        __syncthreads();                                  // B1

        // ---- STEP 2: wave 0 factorizes the 256x8 panel in registers ----
        if (tid < 64) {
            float pa[4][KB];
            #pragma unroll
            for (int q = 0; q < 4; ++q)
                #pragma unroll
                for (int c = 0; c < KB; ++c) pa[q][c] = s_panel[q*64+lane][c];

            int pvt[KB];
            #pragma unroll
            for (int kk = 0; kk < KB; ++kk) {
                const int k  = k0 + kk;
                const int sk = k >> 6, kl = k & 63;
                // argmax over rows >= k of |panel col kk|
                float bv = -1.0f; int bi = NP;
                #pragma unroll
                for (int q = 0; q < 4; ++q) {
                    int r = q*64 + lane;
                    float av = (r >= k) ? fabsf(pa[q][kk]) : -1.0f;
                    if (av > bv) { bv = av; bi = r; }
                }
                #pragma unroll
                for (int off = 32; off; off >>= 1) {
                    float ov = __shfl_xor(bv, off);
                    int   oi = __shfl_xor(bi, off);
                    if (ov > bv || (ov == bv && oi < bi)) { bv = ov; bi = oi; }
                }
                // post-reduce bi is wave-uniform -> pin to SGPR
                const int p = __builtin_amdgcn_readfirstlane(bi);
                const int sp = p >> 6, pl = p & 63;
                pvt[kk] = p;
                // FULL panel-row swap k<->p (all KB cols, incl. L cols c<kk);
                // urow[] captures the post-swap pivot row (uniform -> SGPR)
                float urow[KB];
                #pragma unroll
                for (int c = 0; c < KB; ++c) {
                    float vk, vp;
                    GETSH(vk, c, sk, kl);
                    GETSH(vp, c, sp, pl);
                    if (lane == kl) SETPA(sk, c, vp);
                    if (lane == pl) SETPA(sp, c, vk);
                    urow[c] = rf_f32(vp);
                }
                const float pv = urow[kk];
                if (lane == 0) s_piv[k] = (p != k) ? -pv : pv;
                const float rp = rf_f32(1.0f / pv);
                #pragma unroll
                for (int q = 0; q < 4; ++q) {
                    int r = q*64 + lane;
                    if (r > k) pa[q][kk] *= rp;
                }
                #pragma unroll
                for (int c = kk+1; c < KB; ++c) {
                    #pragma unroll
                    for (int q = 0; q < 4; ++q) {
                        int r = q*64 + lane;
                        if (r > k) pa[q][c] = fmaf(-pa[q][kk], urow[c], pa[q][c]);
                    }
                }
            }
            // write back factored panel + pivots
            #pragma unroll
            for (int q = 0; q < 4; ++q)
                #pragma unroll
                for (int c = 0; c < KB; ++c) s_panel[q*64+lane][c] = pa[q][c];
            if (lane == 0) {
                s_p[0]=pvt[0]; s_p[1]=pvt[1]; s_p[2]=pvt[2]; s_p[3]=pvt[3];
                s_p[4]=pvt[4]; s_p[5]=pvt[5]; s_p[6]=pvt[6]; s_p[7]=pvt[7];
            }
            // in-register swap simulation on 16 tracked positions
            int l8 = lane - 8;
            int psel = pvt[0];
            psel = (l8==1)?pvt[1]:psel; psel = (l8==2)?pvt[2]:psel;
            psel = (l8==3)?pvt[3]:psel; psel = (l8==4)?pvt[4]:psel;
            psel = (l8==5)?pvt[5]:psel; psel = (l8==6)?pvt[6]:psel;
            psel = (l8==7)?pvt[7]:psel;
            const int mypos = (lane < 8) ? (k0 + lane) : psel;
            int cur = mypos;
            #pragma unroll
            for (int s = 0; s < KB; ++s) {
                int cA = __shfl(cur, s);        // content at position k0+s
                int cB = __shfl(cur, 8+s);      // content at position pvt[s]
                int ks = k0 + s, ps = pvt[s];
                if (mypos == ks) cur = cB;
                else if (mypos == ps) cur = cA;
            }
            if (lane < 16) s_src[mypos] = cur;
            if (lane < 8) {
                int c = cur, slot = 8;
                slot = (pvt[0]==c)? 8:slot; slot = (pvt[1]==c)? 9:slot;
                slot = (pvt[2]==c)?10:slot; slot = (pvt[3]==c)?11:slot;
                slot = (pvt[4]==c)?12:slot; slot = (pvt[5]==c)?13:slot;
                slot = (pvt[6]==c)?14:slot; slot = (pvt[7]==c)?15:slot;
                if (c >= k0 && c < k0+KB) slot = c - k0;
                s_uslot[lane] = slot;
            }
        }
        __syncthreads();                                  // B2

        int pp[KB];
        #pragma unroll
        for (int s = 0; s < KB; ++s) pp[s] = s_p[s];

        // ---- STEP 3: stage affected rows (pre-swap content, by position) ----
        if (i >= k0 && i < k0+KB) {
            const int sl = i - k0;
            #pragma unroll
            for (int u = 0; u < 32; ++u) {
                float4 v; v.x=a[u*4]; v.y=a[u*4+1]; v.z=a[u*4+2]; v.w=a[u*4+3];
                *reinterpret_cast<float4*>(&s_stage[sl][jbase+u*4]) = v;
            }
        }
        #pragma unroll
        for (int s = 0; s < KB; ++s) {
            if (i == pp[s]) {
                #pragma unroll
                for (int u = 0; u < 32; ++u) {
                    float4 v; v.x=a[u*4]; v.y=a[u*4+1]; v.z=a[u*4+2]; v.w=a[u*4+3];
                    *reinterpret_cast<float4*>(&s_stage[KB+s][jbase+u*4]) = v;
                }
            }
        }
        __syncthreads();                                  // B3

        // ---- STEP 4a: apply row permutation from stage ----
        {
            const int sr = s_src[i];
            if (sr != i) {
                int slot = 8;
                #pragma unroll
                for (int s = 0; s < KB; ++s) slot = (pp[s]==sr) ? KB+s : slot;
                if (sr >= k0 && sr < k0+KB) slot = sr - k0;
                #pragma unroll
                for (int u = 0; u < 32; ++u) {
                    float4 v = *reinterpret_cast<const float4*>(&s_stage[slot][jbase+u*4]);
                    a[u*4+0]=v.x; a[u*4+1]=v.y; a[u*4+2]=v.z; a[u*4+3]=v.w;
                }
            }
        }
        // ---- STEP 4b: TRSM of U block, column-parallel (jc==0, col j=i) ----
        if (jc == 0) {
            const int j = i;
            int us[KB];
            #pragma unroll
            for (int m = 0; m < KB; ++m) us[m] = s_uslot[m];
            float uv[KB];
            #pragma unroll
            for (int m = 0; m < KB; ++m) {
                float v = s_stage[us[m]][j];
                #pragma unroll
                for (int s = 0; s < KB; ++s)
                    if (s < m) v = fmaf(-s_panel[k0+m][s], uv[s], v);
                uv[m] = v;
                s_U[m][j] = v;
            }
        }
        __syncthreads();                                  // B4

        // ---- STEP 5: rank-8 trailing update ----
        if (i >= k0 + KB) {
            float L[KB];
            #pragma unroll
            for (int m = 0; m < KB; ++m) L[m] = s_panel[i][m];
            #pragma unroll
            for (int u = 0; u < 32; ++u) {
                if (jbase + u*4 + 3 >= k0 + KB) {
                    float c0=a[u*4], c1=a[u*4+1], c2=a[u*4+2], c3=a[u*4+3];
                    #pragma unroll
                    for (int m = 0; m < KB; ++m) {
                        const float4 uv = *reinterpret_cast<const float4*>(&s_U[m][jbase+u*4]);
                        c0 = fmaf(-L[m], uv.x, c0);
                        c1 = fmaf(-L[m], uv.y, c1);
                        c2 = fmaf(-L[m], uv.z, c2);
                        c3 = fmaf(-L[m], uv.w, c3);
                    }
                    a[u*4]=c0; a[u*4+1]=c1; a[u*4+2]=c2; a[u*4+3]=c3;
                }
            }
        }
    }
    __syncthreads();

    // ---- logdet = sum log|piv| (f64 accum), sign = parity of negatives ----
    if (tid < 64) {
        double ld = 0.0; int neg = 0;
        #pragma unroll
        for (int q = 0; q < 4; ++q) {
            float pv = s_piv[q*64 + tid];
            ld  += (double)logf(fabsf(pv));
            neg ^= (pv < 0.0f) ? 1 : 0;
        }
        #pragma unroll
        for (int off = 32; off; off >>= 1) {
            ld  += __shfl_xor(ld, off);
            neg ^= __shfl_xor(neg, off);
        }
        if (tid == 0) { out[0] = neg ? -1.0f : 1.0f; out[1] = (float)ld; }
    }
}

extern "C" void kernel_launch(void* const* d_in, const int* in_sizes, int n_in,
                              void* d_out, int out_size, void* d_ws, size_t ws_size,
                              hipStream_t stream)
{
    const float* x  = (const float*)d_in[0];
    const float* W0 = (const float*)d_in[1];
    const float* b0 = (const float*)d_in[2];
    const float* W1 = (const float*)d_in[3];
    const float* b1 = (const float*)d_in[4];
    const float* W2 = (const float*)d_in[5];
    const float* b2 = (const float*)d_in[6];
    float* out    = (float*)d_out;
    float* slater = (float*)d_ws;           // 256*256*4 = 256 KB scratch

    k_mlp<<<dim3(NP, NP/BT), 256, 0, stream>>>(x, W0, b0, W1, b1, W2, b2, slater);
    k_lu_blk<<<1, 512, 0, stream>>>(slater, out);
}